// Round 3
// baseline (580.360 us; speedup 1.0000x reference)
//
#include <hip/hip_runtime.h>

// Problem constants (from reference): N=128, Cin=64, T=128, V=25, O=64, R=8
#define EPSV 1e-5f
constexpr int NN = 128, CIN = 64, TT = 128, VV = 25, OO = 64, RR = 8;
constexpr int TVQ   = TT * VV;        // 3200  (per-channel plane)
constexpr int XSAMP = CIN * TVQ;      // 204800 (per-sample x)
constexpr int YSAMP = OO * TT * VV;   // 819200 (per-sample y)
constexpr int YS2_SAMP = VV * OO * 28;  // 44800: ys2[n][u][o][28] (v padded 25->28)
constexpr int X3_SAMP  = TVQ * OO;      // 204800: x3T[n][p][o], p = t*25+v

// ---------------------------------------------------------------- zero scratch
__global__ __launch_bounds__(256) void kZero(float* __restrict__ p, int n)
{
    int i = blockIdx.x * 256 + threadIdx.x;
    if (i < n) p[i] = 0.f;
}

// ---------------------------------------------------------------- kernel G
// Per-sample Gram matrix G[64][64] = sum_{t,v} x xT and temporal sums
// xbar[64][25] = sum_t x. Replaces the old conv1/conv2 pass: GroupNorm stats
// and temporal means are linear/quadratic in x, so branch 1/2 need only G
// and xbar (see kB). Grid (2, N): each block does a t-half (1600 p).
// LDS tile: 64 p x 72 stride, granule-rotated (c-granule (c>>3) rotated by
// (p>>3)&7) so staging writes are ~4-way and compute b128 reads 2-way (free).
// 8x8 register tile per thread (ti,tj); 4 p-subgroups g reduced pairwise in
// LDS, then global atomicAdd (2 blocks/sample).
__global__ __launch_bounds__(256) void kG(const float* __restrict__ x,
    float* __restrict__ Gg, float* __restrict__ xbarg)
{
    __shared__ float xt[4608];           // tile (64*72); aliased as buf0 later
    __shared__ float bufB[64 * 68];
    __shared__ float xbs[64 * 26];
    const int tid  = threadIdx.x;
    const int half = blockIdx.x;         // 0..1
    const int n    = blockIdx.y;
    const int g  = tid >> 6;             // p-subgroup 0..3 (16 p each)
    const int t6 = tid & 63;
    const int ti = t6 >> 3, tj = t6 & 7; // 8x8 c-tile coords

    for (int e = tid; e < 64 * 26; e += 256) xbs[e] = 0.f;

    float acc[8][8];
    #pragma unroll
    for (int a = 0; a < 8; ++a)
        #pragma unroll
        for (int b = 0; b < 8; ++b) acc[a][b] = 0.f;

    const float* xb = x + (size_t)n * XSAMP + half * 1600;
    const int vbase = half * 1600;
    #pragma unroll 1
    for (int k = 0; k < 25; ++k) {
        __syncthreads();                 // prior tile reads done
        const int pb = k * 64;
        for (int e = tid; e < 1024; e += 256) {
            int c = e >> 4, p4 = e & 15;
            float4 xv = *(const float4*)(xb + c * TVQ + pb + p4 * 4);
            float vals[4] = {xv.x, xv.y, xv.z, xv.w};
            #pragma unroll
            for (int j = 0; j < 4; ++j) {
                int p   = p4 * 4 + j;
                int rot = (p >> 3) & 7;
                xt[p * 72 + (((c >> 3) + rot) & 7) * 8 + (c & 7)] = vals[j];
                int vg = (vbase + pb + p) % VV;
                atomicAdd(&xbs[c * 26 + vg], vals[j]);
            }
        }
        __syncthreads();
        #pragma unroll
        for (int pp = 0; pp < 16; ++pp) {
            const int row = g * 16 + pp;
            const float* xr = &xt[row * 72];
            const int rot = (row >> 3) & 7;
            const float* pi = xr + ((ti + rot) & 7) * 8;
            const float* pj = xr + ((tj + rot) & 7) * 8;
            float4 xi0 = *(const float4*)(pi);
            float4 xi1 = *(const float4*)(pi + 4);
            float4 xj0 = *(const float4*)(pj);
            float4 xj1 = *(const float4*)(pj + 4);
            float xiv[8] = {xi0.x, xi0.y, xi0.z, xi0.w, xi1.x, xi1.y, xi1.z, xi1.w};
            float xjv[8] = {xj0.x, xj0.y, xj0.z, xj0.w, xj1.x, xj1.y, xj1.z, xj1.w};
            #pragma unroll
            for (int a = 0; a < 8; ++a)
                #pragma unroll
                for (int b = 0; b < 8; ++b)
                    acc[a][b] += xiv[a] * xjv[b];
        }
    }
    __syncthreads();
    // pairwise reduction of the 4 group-partials: g0,g2 -> buf0; g1,g3 -> bufB
    float* buf0 = xt;                    // reuse tile buffer (4352 <= 4608)
    if (g == 0) {
        #pragma unroll
        for (int a = 0; a < 8; ++a)
            #pragma unroll
            for (int b = 0; b < 8; ++b)
                buf0[(ti * 8 + a) * 68 + tj * 8 + b] = acc[a][b];
    } else if (g == 1) {
        #pragma unroll
        for (int a = 0; a < 8; ++a)
            #pragma unroll
            for (int b = 0; b < 8; ++b)
                bufB[(ti * 8 + a) * 68 + tj * 8 + b] = acc[a][b];
    }
    __syncthreads();
    if (g == 2) {
        #pragma unroll
        for (int a = 0; a < 8; ++a)
            #pragma unroll
            for (int b = 0; b < 8; ++b)
                buf0[(ti * 8 + a) * 68 + tj * 8 + b] += acc[a][b];
    } else if (g == 3) {
        #pragma unroll
        for (int a = 0; a < 8; ++a)
            #pragma unroll
            for (int b = 0; b < 8; ++b)
                bufB[(ti * 8 + a) * 68 + tj * 8 + b] += acc[a][b];
    }
    __syncthreads();
    for (int e = tid; e < 4096; e += 256) {
        int r = e >> 6, cl = e & 63;
        atomicAdd(&Gg[(size_t)n * 4096 + e],
                  buf0[r * 68 + cl] + bufB[r * 68 + cl]);
    }
    for (int e = tid; e < 1600; e += 256) {
        int c = e / VV, v = e % VV;
        atomicAdd(&xbarg[(size_t)n * 1600 + e], xbs[c * 26 + v]);
    }
}

// ---------------------------------------------------------------- kernel B
__device__ __forceinline__ float tanh_fast(float v)
{
    float e = __expf(2.f * v);
    return 1.f - 2.f / (e + 1.f);    // safe at +/-inf of e
}

// Computes GroupNorm stats from G/xbar (mu = linear, E[z^2] = w^T G w terms),
// then x1/x2 [8][25], then the 625-point relational tensor + w4 GEMM.
// Output layout ys2[n][u][o][28]: v contiguous (padded, pads written 0) so
// kC2 reads float4 of v -> 8 FMA per load.
__global__ __launch_bounds__(512) void kB(
    const float* __restrict__ Gg, const float* __restrict__ xbarg,
    const float* __restrict__ w1, const float* __restrict__ b1,
    const float* __restrict__ g1, const float* __restrict__ be1,
    const float* __restrict__ w2, const float* __restrict__ b2,
    const float* __restrict__ g2, const float* __restrict__ be2,
    const float* __restrict__ Amat, const float* __restrict__ w4,
    const float* __restrict__ b4, float* __restrict__ ys2)
{
    __shared__ float x1g[RR * VV], x2g[RR * VV];
    __shared__ float w4l[OO * RR];
    __shared__ float b4l[OO];
    __shared__ float wl1[RR * CIN], wl2[RR * CIN];
    __shared__ float xbl[1600];
    __shared__ float qred[16], lin[16];
    __shared__ float sxc[CIN];
    __shared__ float mss[4];       // mu1, rs1, mu2, rs2
    const int tid = threadIdx.x;
    const int bx  = blockIdx.x;    // 0..4
    const int n   = blockIdx.y;

    if (tid < 512) { w4l[tid] = w4[tid]; wl1[tid] = w1[tid]; wl2[tid] = w2[tid]; }
    if (tid < OO) b4l[tid] = b4[tid];
    for (int e = tid; e < 1600; e += 512) xbl[e] = xbarg[(size_t)n * 1600 + e];
    __syncthreads();

    if (tid < CIN) {               // sxc[c] = sum_{t,v} x = sum_v xbar
        float s = 0.f;
        for (int v = 0; v < VV; ++v) s += xbl[tid * VV + v];
        sxc[tid] = s;
    }
    {   // quadratic terms q[br*8+r] = w_r^T G w_r  (32 threads per (br,r))
        int k = tid >> 5, ci = tid & 31;
        int br = k >> 3, r = k & 7;
        const float* wv = br ? wl2 : wl1;
        const float* Gn = Gg + (size_t)n * 4096;
        float part = 0.f;
        #pragma unroll
        for (int h = 0; h < 2; ++h) {
            int c = ci + 32 * h;
            float s = 0.f;
            for (int cj = 0; cj < 64; ++cj) s += Gn[c * 64 + cj] * wv[r * 64 + cj];
            part += wv[r * 64 + c] * s;
        }
        #pragma unroll
        for (int off = 16; off; off >>= 1) part += __shfl_down(part, off, 32);
        if ((tid & 31) == 0) qred[k] = part;
    }
    __syncthreads();
    if (tid < 16) {                // linear terms w_r . sxc
        int br = tid >> 3, r = tid & 7;
        const float* wv = br ? wl2 : wl1;
        float s = 0.f;
        for (int c = 0; c < 64; ++c) s += wv[r * 64 + c] * sxc[c];
        lin[tid] = s;
    }
    __syncthreads();
    if (tid < 2) {
        const float* bb = tid ? b2 : b1;
        float sl = 0.f, sq = 0.f, sb = 0.f, sb2 = 0.f;
        for (int r = 0; r < 8; ++r) {
            float l = lin[tid * 8 + r];
            sl += l;
            sq += qred[tid * 8 + r] + 2.f * bb[r] * l;
            sb += bb[r]; sb2 += bb[r] * bb[r];
        }
        float mu  = (sl + 3200.f * sb) / 25600.f;
        float var = (sq + 3200.f * sb2) / 25600.f - mu * mu;
        mss[tid * 2]     = mu;
        mss[tid * 2 + 1] = rsqrtf(var + EPSV);
    }
    __syncthreads();
    if (tid < 400) {               // x1/x2 [r][v]: GN(temporal mean)
        int br = tid / 200, i = tid % 200, r = i / VV, v = i % VV;
        const float* wv = br ? wl2 : wl1;
        float d = 0.f;
        for (int c = 0; c < 64; ++c) d += wv[r * 64 + c] * xbl[c * VV + v];
        float mean_t = d * (1.f / 128.f) + (br ? b2[r] : b1[r]);
        float val = (br ? g2[r] : g1[r]) * (mean_t - mss[br * 2]) * mss[br * 2 + 1]
                    + (br ? be2[r] : be1[r]);
        if (br == 0) x1g[i] = val; else x2g[i] = val;
    }
    __syncthreads();

    float* yn = ys2 + (size_t)n * YS2_SAMP;
    const int pend = (bx + 1) * 125;     // 5*125 = 625 exactly
    for (int p = bx * 125 + tid; p < pend; p += 512) {
        int u = p / VV, v = p % VV;
        float Av = Amat[p];
        float ys[RR];
        #pragma unroll
        for (int r = 0; r < RR; ++r) {
            float d = x1g[r * VV + u] - x1g[r * VV + v];
            float m = x2g[r * VV + u] * x2g[r * VV + v];
            ys[r] = tanh_fast(d) + tanh_fast(m) + Av;   // ALPHA = 1
        }
        float* dst = yn + u * (OO * 28) + v;
        const bool pad = (v >= 22);      // v+3 covers pads 25..27
        for (int o = 0; o < OO; ++o) {
            float a = b4l[o];
            #pragma unroll
            for (int r = 0; r < RR; ++r) a += w4l[o * RR + r] * ys[r];
            dst[o * 28] = a;
            if (pad) dst[o * 28 + 3] = 0.f;
        }
    }
}

// ---------------------------------------------------------------- kernel C1
// conv3 as a per-sample [64o x 64c] x [64c x 3200p] fp32 GEMM (unchanged).
__global__ __launch_bounds__(256) void kC1(const float* __restrict__ x,
    const float* __restrict__ w3, const float* __restrict__ b3,
    float* __restrict__ x3T)
{
    __shared__ float wt[CIN * 68];       // wt[c][o], stride 68 (17 KB)
    const int tid = threadIdx.x;
    const int n   = blockIdx.y;
    const int oq  = tid & 7;             // o in [8*oq, 8*oq+8)
    const int pg  = tid >> 3;            // 0..31
    const int p0  = blockIdx.x * 256 + pg * 8;

    for (int e = tid; e < CIN * OO; e += 256) {
        int o = e >> 6, c = e & 63;
        wt[c * 68 + o] = w3[e];
    }
    __syncthreads();

    float acc[8][8];                     // [o_local][p_local]
    #pragma unroll
    for (int i = 0; i < 8; ++i)
        #pragma unroll
        for (int j = 0; j < 8; ++j) acc[i][j] = 0.f;

    const bool act = (p0 < TVQ);
    const float* xp = x + (size_t)n * XSAMP + p0;
    if (act) {
        #pragma unroll 4
        for (int c = 0; c < CIN; ++c) {
            const float* xc = xp + c * TVQ;
            float4 xa = *(const float4*)(xc);
            float4 xb = *(const float4*)(xc + 4);
            const float* wr = &wt[c * 68 + oq * 8];
            float4 wa = *(const float4*)(wr);
            float4 wb = *(const float4*)(wr + 4);
            float xv[8] = {xa.x, xa.y, xa.z, xa.w, xb.x, xb.y, xb.z, xb.w};
            float wv[8] = {wa.x, wa.y, wa.z, wa.w, wb.x, wb.y, wb.z, wb.w};
            #pragma unroll
            for (int i = 0; i < 8; ++i)
                #pragma unroll
                for (int j = 0; j < 8; ++j)
                    acc[i][j] += wv[i] * xv[j];
        }
    }

    float bo[8];
    #pragma unroll
    for (int i = 0; i < 8; ++i) bo[i] = b3[oq * 8 + i];
    if (act) {
        float* dst = x3T + (size_t)n * X3_SAMP + (size_t)p0 * OO + oq * 8;
        #pragma unroll
        for (int j = 0; j < 8; ++j) {
            float4 s0, s1;
            s0.x = acc[0][j] + bo[0]; s0.y = acc[1][j] + bo[1];
            s0.z = acc[2][j] + bo[2]; s0.w = acc[3][j] + bo[3];
            s1.x = acc[4][j] + bo[4]; s1.y = acc[5][j] + bo[5];
            s1.z = acc[6][j] + bo[6]; s1.w = acc[7][j] + bo[7];
            *(float4*)(dst + j * OO)     = s0;
            *(float4*)(dst + j * OO + 4) = s1;
        }
    }
}

// ---------------------------------------------------------------- kernel C2
// Aggregation. ys2[u][o][28] is v-contiguous: float4 loads feed 8 FMAs
// (was scalar-equivalent, 2 FMA/load, 675 vmem instr/thread -> 225).
// acc2 padded to 28 with zeros; ys2 pads are written 0 by kB.
__global__ __launch_bounds__(256) void kC2(const float* __restrict__ x3T,
    const float* __restrict__ ys2, float* __restrict__ y)
{
    __shared__ float lds[OO * 101];      // 25.9 KB (output transpose)
    const int tid = threadIdx.x;
    const int tc  = blockIdx.x;          // 0..15
    const int n   = blockIdx.y;
    const int t0  = tc * 8;
    const int o2  = tid & 63;
    const int th2 = tid >> 6;            // 0..3

    const float* xb = x3T + (size_t)n * X3_SAMP;
    float acc2[2][28];
    #pragma unroll
    for (int row = 0; row < 2; ++row) {
        const int t = t0 + 2 * th2 + row;
        #pragma unroll
        for (int v = 0; v < VV; ++v)
            acc2[row][v] = xb[(size_t)(t * VV + v) * OO + o2];
        acc2[row][25] = 0.f; acc2[row][26] = 0.f; acc2[row][27] = 0.f;
    }

    const float* yo = ys2 + (size_t)n * YS2_SAMP + o2 * 28;
    float res[2][VV];
    #pragma unroll
    for (int u = 0; u < VV; ++u) {
        const float* yu = yo + u * (OO * 28);
        float r0 = 0.f, r1 = 0.f;
        #pragma unroll
        for (int v4 = 0; v4 < 28; v4 += 4) {
            float4 w = *(const float4*)(yu + v4);
            r0 += w.x * acc2[0][v4]     + w.y * acc2[0][v4 + 1]
                + w.z * acc2[0][v4 + 2] + w.w * acc2[0][v4 + 3];
            r1 += w.x * acc2[1][v4]     + w.y * acc2[1][v4 + 1]
                + w.z * acc2[1][v4 + 2] + w.w * acc2[1][v4 + 3];
        }
        res[0][u] = r0;
        res[1][u] = r1;
    }

    float* yb = y + (size_t)n * YSAMP + t0 * VV;
    #pragma unroll 1
    for (int half = 0; half < 2; ++half) {
        __syncthreads();
        if ((th2 >> 1) == half) {
            #pragma unroll
            for (int row = 0; row < 2; ++row) {
                const int tl = (2 * th2 + row) & 3;
                #pragma unroll
                for (int u = 0; u < VV; ++u)
                    lds[o2 * 101 + tl * VV + u] = res[row][u];
            }
        }
        __syncthreads();
        for (int e = tid; e < 6400; e += 256) {
            int o = e / 100, m = e % 100;
            yb[o * TVQ + half * 100 + m] = lds[o * 101 + m];
        }
    }
}

// ---------------------------------------------------------------- kernel C (fallback)
// Fused conv3+aggregation, used only if the workspace cannot hold even one
// sample of x3T. Updated for the ys2[u][o][28] layout (correctness path).
__global__ __launch_bounds__(256) void kC(
    const float* __restrict__ x, const float* __restrict__ w3,
    const float* __restrict__ b3, const float* __restrict__ ys2,
    float* __restrict__ y)
{
    __shared__ float lds[7168];          // 28672 B
    const int tid = threadIdx.x;
    const int tc  = blockIdx.x;          // 0..15
    const int n   = blockIdx.y;
    const int t0  = tc * 8;

    const int og = tid >> 3;             // 0..31
    const int th = tid & 7;              // 0..7 (t-row)
    const int o0 = og * 2;

    float acc[2][VV];
    #pragma unroll
    for (int j = 0; j < 2; ++j)
        #pragma unroll
        for (int v = 0; v < VV; ++v) acc[j][v] = 0.f;

    const float* xn = x + (size_t)n * XSAMP + t0 * VV;
    #pragma unroll 1
    for (int cpass = 0; cpass < 2; ++cpass) {
        __syncthreads();
        for (int e4 = tid; e4 < 32 * 50; e4 += 256) {
            int cl = e4 / 50, r4 = (e4 % 50) * 4;
            float4 tv = *(const float4*)(xn + (cpass * 32 + cl) * TVQ + r4);
            float a[4] = {tv.x, tv.y, tv.z, tv.w};
            #pragma unroll
            for (int j = 0; j < 4; ++j) {
                int rem = r4 + j;
                lds[cl * 224 + (rem / VV) * 28 + (rem % VV)] = a[j];
            }
        }
        __syncthreads();
        #pragma unroll 1
        for (int q = 0; q < 2; ++q) {
            float w3q[2][16];
            #pragma unroll
            for (int j = 0; j < 2; ++j)
                #pragma unroll
                for (int k4 = 0; k4 < 4; ++k4) {
                    float4 wv = *(const float4*)(w3 + (o0 + j) * CIN
                                                 + cpass * 32 + q * 16 + k4 * 4);
                    w3q[j][k4*4+0] = wv.x; w3q[j][k4*4+1] = wv.y;
                    w3q[j][k4*4+2] = wv.z; w3q[j][k4*4+3] = wv.w;
                }
            #pragma unroll
            for (int ci = 0; ci < 16; ++ci) {
                const float* p = &lds[(q * 16 + ci) * 224 + th * 28];
                float4 a0 = *(const float4*)(p + 0);
                float4 a1 = *(const float4*)(p + 4);
                float4 a2 = *(const float4*)(p + 8);
                float4 a3 = *(const float4*)(p + 12);
                float4 a4 = *(const float4*)(p + 16);
                float4 a5 = *(const float4*)(p + 20);
                float  a6 = p[24];
                #pragma unroll
                for (int j = 0; j < 2; ++j) {
                    const float w = w3q[j][ci];
                    float* a = acc[j];
                    a[0]  += w*a0.x; a[1]  += w*a0.y; a[2]  += w*a0.z; a[3]  += w*a0.w;
                    a[4]  += w*a1.x; a[5]  += w*a1.y; a[6]  += w*a1.z; a[7]  += w*a1.w;
                    a[8]  += w*a2.x; a[9]  += w*a2.y; a[10] += w*a2.z; a[11] += w*a2.w;
                    a[12] += w*a3.x; a[13] += w*a3.y; a[14] += w*a3.z; a[15] += w*a3.w;
                    a[16] += w*a4.x; a[17] += w*a4.y; a[18] += w*a4.z; a[19] += w*a4.w;
                    a[20] += w*a5.x; a[21] += w*a5.y; a[22] += w*a5.z; a[23] += w*a5.w;
                    a[24] += w*a6;
                }
            }
        }
    }

    const int o2  = tid & 63;
    const int th2 = tid >> 6;            // 0..3, owns t = {2*th2, 2*th2+1}
    const float bias = b3[o2];
    float acc2[2][VV];

    #pragma unroll 1
    for (int half = 0; half < 2; ++half) {
        __syncthreads();
        if ((th >> 2) == half) {
            const int tl = th & 3;
            #pragma unroll
            for (int j = 0; j < 2; ++j)
                #pragma unroll
                for (int v = 0; v < VV; ++v)
                    lds[tl * 1601 + (o0 + j) * VV + v] = acc[j][v];
        }
        __syncthreads();
        if ((th2 >> 1) == half) {
            #pragma unroll
            for (int row = 0; row < 2; ++row) {
                const int tl = (2 * th2 + row) & 3;
                #pragma unroll
                for (int v = 0; v < VV; ++v)
                    acc2[row][v] = lds[tl * 1601 + o2 * VV + v];
            }
        }
    }
    #pragma unroll
    for (int row = 0; row < 2; ++row)
        #pragma unroll
        for (int v = 0; v < VV; ++v) acc2[row][v] += bias;

    const float* yT = ys2 + (size_t)n * YS2_SAMP + o2 * 28;
    float res[2][VV];
    #pragma unroll
    for (int u = 0; u < VV; ++u) {
        float r0 = 0.f, r1 = 0.f;
        #pragma unroll
        for (int v = 0; v < VV; ++v) {
            float yv = yT[u * (OO * 28) + v];
            r0 += yv * acc2[0][v];
            r1 += yv * acc2[1][v];
        }
        res[0][u] = r0;
        res[1][u] = r1;
    }

    float* yb = y + (size_t)n * YSAMP + t0 * VV;
    #pragma unroll 1
    for (int half = 0; half < 2; ++half) {
        __syncthreads();
        if ((th2 >> 1) == half) {
            #pragma unroll
            for (int row = 0; row < 2; ++row) {
                const int tl = (2 * th2 + row) & 3;
                #pragma unroll
                for (int u = 0; u < VV; ++u)
                    lds[o2 * 101 + tl * VV + u] = res[row][u];
            }
        }
        __syncthreads();
        for (int e = tid; e < 6400; e += 256) {
            int o = e / 100, m = e % 100;
            yb[o * TVQ + half * 100 + m] = lds[o * 101 + m];
        }
    }
}

// ---------------------------------------------------------------- launch
extern "C" void kernel_launch(void* const* d_in, const int* in_sizes, int n_in,
                              void* d_out, int out_size, void* d_ws, size_t ws_size,
                              hipStream_t stream)
{
    const float* x   = (const float*)d_in[0];
    const float* Am  = (const float*)d_in[1];
    const float* w1  = (const float*)d_in[2];
    const float* b1  = (const float*)d_in[3];
    const float* g1  = (const float*)d_in[4];
    const float* be1 = (const float*)d_in[5];
    const float* w2  = (const float*)d_in[6];
    const float* b2  = (const float*)d_in[7];
    const float* g2  = (const float*)d_in[8];
    const float* be2 = (const float*)d_in[9];
    const float* w3  = (const float*)d_in[10];
    const float* b3  = (const float*)d_in[11];
    const float* w4  = (const float*)d_in[12];
    const float* b4  = (const float*)d_in[13];
    float* y  = (float*)d_out;
    float* ws = (float*)d_ws;
    // workspace: Gg 128*4096 | xbarg 128*1600 | ys2 128*44800 | x3T up to
    // 128*204800 (~105 MB). Total ~131 MB; chunked / fallback if ws smaller.
    float* Gg    = ws;
    float* xbarg = Gg + (size_t)NN * 4096;
    float* ys2   = xbarg + (size_t)NN * 1600;
    float* x3T   = ys2 + (size_t)NN * YS2_SAMP;

    const int nz = NN * 4096 + NN * 1600;      // G + xbar accumulators
    hipLaunchKernelGGL(kZero, dim3((nz + 255) / 256), dim3(256), 0, stream, ws, nz);
    hipLaunchKernelGGL(kG, dim3(2, NN), dim3(256), 0, stream, x, Gg, xbarg);
    hipLaunchKernelGGL(kB, dim3(5, NN), dim3(512), 0, stream,
                       Gg, xbarg, w1, b1, g1, be1, w2, b2, g2, be2, Am, w4, b4, ys2);

    const size_t baseF = (size_t)NN * 4096 + (size_t)NN * 1600
                       + (size_t)NN * YS2_SAMP;
    const size_t wsF   = ws_size / sizeof(float);
    long availF = (long)wsF - (long)baseF;
    int chunk = 0;
    if (availF >= (long)X3_SAMP) {
        long c = availF / (long)X3_SAMP;
        chunk = (c > NN) ? NN : (int)c;
    }
    if (chunk >= 1) {
        for (int n0 = 0; n0 < NN; n0 += chunk) {
            int nc = (NN - n0 < chunk) ? (NN - n0) : chunk;
            hipLaunchKernelGGL(kC1, dim3(13, nc), dim3(256), 0, stream,
                               x + (size_t)n0 * XSAMP, w3, b3, x3T);
            hipLaunchKernelGGL(kC2, dim3(16, nc), dim3(256), 0, stream,
                               x3T, ys2 + (size_t)n0 * YS2_SAMP,
                               y + (size_t)n0 * YSAMP);
        }
    } else {
        hipLaunchKernelGGL(kC, dim3(16, NN), dim3(256), 0, stream,
                           x, w3, b3, ys2, y);
    }
}

// Round 4
// 453.892 us; speedup vs baseline: 1.2786x; 1.2786x over previous
//
#include <hip/hip_runtime.h>

// Problem constants (from reference): N=128, Cin=64, T=128, V=25, O=64, R=8
#define EPSV 1e-5f
constexpr int NN = 128, CIN = 64, TT = 128, VV = 25, OO = 64, RR = 8;
constexpr int TVQ   = TT * VV;        // 3200  (per-channel plane)
constexpr int XSAMP = CIN * TVQ;      // 204800 (per-sample x)
constexpr int YSAMP = OO * TT * VV;   // 819200 (per-sample y)
constexpr int RTV   = RR * TT * VV;   // 25600 (GroupNorm count)
constexpr int S12N  = 2 * RR * VV;    // 400   (s1+s2 per sample)
constexpr int YS2_SAMP = VV * OO * 28;  // 44800: ys2[n][u][o][28] (v padded 25->28)
constexpr int X3_SAMP  = TVQ * OO;      // 204800: x3T[n][p][o], p = t*25+v

// ---------------------------------------------------------------- zero scratch
__global__ __launch_bounds__(256) void kZero(float* __restrict__ p, int n)
{
    int i = blockIdx.x * 256 + threadIdx.x;
    if (i < n) p[i] = 0.f;
}

// ---------------------------------------------------------------- kernel A
// (Proven R0/R2 version, verbatim.) One pass over x. Per block: (n, t-chunk
// of 32). 200 threads own 4 consecutive (t,v) points each (float4 loads,
// coalesced). Outputs: s12g[n][400] = sum_t conv_pre_bias, ssqg[n][2] =
// sum of squares (bias included).
__global__ __launch_bounds__(256) void kA(const float* __restrict__ x,
    const float* __restrict__ w1, const float* __restrict__ b1,
    const float* __restrict__ w2, const float* __restrict__ b2,
    float* __restrict__ s12g, float* __restrict__ ssqg)
{
    __shared__ float wt1[CIN * RR], wt2[CIN * RR];   // transposed [c][r]
    __shared__ float s1l[RR * VV], s2l[RR * VV];
    __shared__ float redA[4], redB[4];
    const int tid = threadIdx.x;
    const int tc  = blockIdx.x;   // 0..3  (32 t each)
    const int n   = blockIdx.y;

    for (int e = tid; e < CIN * RR; e += 256) {
        int r = e >> 6, c = e & 63;
        wt1[c * RR + r] = w1[e];
        wt2[c * RR + r] = w2[e];
    }
    for (int e = tid; e < 2 * RR * VV; e += 256) {
        if (e < RR * VV) s1l[e] = 0.f; else s2l[e - RR * VV] = 0.f;
    }
    __syncthreads();

    float acc1[4][RR], acc2[4][RR];
    #pragma unroll
    for (int j = 0; j < 4; ++j)
        #pragma unroll
        for (int r = 0; r < RR; ++r) { acc1[j][r] = 0.f; acc2[j][r] = 0.f; }

    const bool active = (tid < 200);
    const int p0 = tid * 4;                       // flat (t,v) offset in chunk
    const float* xb = x + (size_t)n * XSAMP + tc * 800 + p0;
    if (active) {
        #pragma unroll 4
        for (int c = 0; c < CIN; ++c) {
            float4 xv  = *(const float4*)(xb + c * TVQ);
            float4 wa1 = *(const float4*)(&wt1[c * RR]);
            float4 wb1 = *(const float4*)(&wt1[c * RR + 4]);
            float4 wa2 = *(const float4*)(&wt2[c * RR]);
            float4 wb2 = *(const float4*)(&wt2[c * RR + 4]);
            float xj[4]  = {xv.x, xv.y, xv.z, xv.w};
            float w1v[8] = {wa1.x, wa1.y, wa1.z, wa1.w, wb1.x, wb1.y, wb1.z, wb1.w};
            float w2v[8] = {wa2.x, wa2.y, wa2.z, wa2.w, wb2.x, wb2.y, wb2.z, wb2.w};
            #pragma unroll
            for (int j = 0; j < 4; ++j)
                #pragma unroll
                for (int r = 0; r < RR; ++r) {
                    acc1[j][r] += w1v[r] * xj[j];
                    acc2[j][r] += w2v[r] * xj[j];
                }
        }
    }

    float b1r[RR], b2r[RR];
    #pragma unroll
    for (int r = 0; r < RR; ++r) { b1r[r] = b1[r]; b2r[r] = b2[r]; }

    float ssq1 = 0.f, ssq2 = 0.f;
    if (active) {
        #pragma unroll
        for (int j = 0; j < 4; ++j) {
            int v = (p0 + j) % VV;
            #pragma unroll
            for (int r = 0; r < RR; ++r) {
                float c1 = acc1[j][r] + b1r[r]; ssq1 += c1 * c1;
                float c2 = acc2[j][r] + b2r[r]; ssq2 += c2 * c2;
                atomicAdd(&s1l[r * VV + v], acc1[j][r]);
                atomicAdd(&s2l[r * VV + v], acc2[j][r]);
            }
        }
    }
    #pragma unroll
    for (int off = 32; off > 0; off >>= 1) {
        ssq1 += __shfl_down(ssq1, off);
        ssq2 += __shfl_down(ssq2, off);
    }
    if ((tid & 63) == 0) { redA[tid >> 6] = ssq1; redB[tid >> 6] = ssq2; }
    __syncthreads();                               // LDS atomics + redA/B done
    for (int e = tid; e < S12N; e += 256) {
        float pv = (e < RR * VV) ? s1l[e] : s2l[e - RR * VV];
        atomicAdd(&s12g[n * S12N + e], pv);
    }
    if (tid == 0) {
        atomicAdd(&ssqg[n * 2 + 0], redA[0] + redA[1] + redA[2] + redA[3]);
        atomicAdd(&ssqg[n * 2 + 1], redB[0] + redB[1] + redB[2] + redB[3]);
    }
}

// ---------------------------------------------------------------- kernel B
__device__ __forceinline__ float tanh_fast(float v)
{
    float e = __expf(2.f * v);
    return 1.f - 2.f / (e + 1.f);    // safe at +/-inf of e
}

// REWRITE: one block per sample (grid NN, 512 threads). The old version had
// only 125/512 threads active and 64-89 scattered scalar stores per thread
// (each wave store = 64 distinct cache lines) -> ~155-190 us, the hidden #2
// kernel. Now: stats preamble once, ys[625][8] staged in LDS (stride 9,
// conflict-free), then ALL 512 threads emit ys2[u][o][28] as fully coalesced
// float4 stores (~22/thread, contiguous 1KB per wave instr). Pads written 0.
__global__ __launch_bounds__(512) void kB(
    const float* __restrict__ s12g, const float* __restrict__ ssqg,
    const float* __restrict__ b1, const float* __restrict__ g1, const float* __restrict__ be1,
    const float* __restrict__ b2, const float* __restrict__ g2, const float* __restrict__ be2,
    const float* __restrict__ Amat, const float* __restrict__ w4, const float* __restrict__ b4,
    float* __restrict__ ys2)
{
    __shared__ float x1g[RR * VV], x2g[RR * VV];
    __shared__ float w4t[RR * OO];       // transposed [r][o]
    __shared__ float b4l[OO];
    __shared__ float ysl[625 * 9];       // 22.5 KB, stride 9 (banks spread)
    __shared__ float stats[2];
    __shared__ float mss[4];             // mu1, rs1, mu2, rs2
    const int tid = threadIdx.x;
    const int n   = blockIdx.x;

    if (tid < 2) stats[tid] = 0.f;
    if (tid < OO * RR) {                 // w4[o][r] -> w4t[r][o]
        int o = tid >> 3, r = tid & 7;
        w4t[r * OO + o] = w4[tid];
    }
    if (tid < OO) b4l[tid] = b4[tid];
    __syncthreads();

    float sv = 0.f;
    if (tid < S12N) {
        sv = s12g[n * S12N + tid];
        atomicAdd(&stats[tid / (RR * VV)], sv);
    }
    __syncthreads();
    if (tid == 0) {
        float sb1 = 0.f, sb2 = 0.f;
        for (int r = 0; r < RR; ++r) { sb1 += b1[r]; sb2 += b2[r]; }
        float mu1 = (stats[0] + (float)(TT * VV) * sb1) / (float)RTV;
        float mu2 = (stats[1] + (float)(TT * VV) * sb2) / (float)RTV;
        float var1 = ssqg[n * 2 + 0] / (float)RTV - mu1 * mu1;
        float var2 = ssqg[n * 2 + 1] / (float)RTV - mu2 * mu2;
        mss[0] = mu1; mss[1] = rsqrtf(var1 + EPSV);
        mss[2] = mu2; mss[3] = rsqrtf(var2 + EPSV);
    }
    __syncthreads();
    if (tid < S12N) {
        int br = tid / (RR * VV);
        int i  = tid % (RR * VV);
        int r  = i / VV;
        float mu = mss[br * 2], rs = mss[br * 2 + 1];
        float mean_t = sv / (float)TT + (br ? b2[r] : b1[r]);
        float g  = br ? g2[r]  : g1[r];
        float be = br ? be2[r] : be1[r];
        float val = g * (mean_t - mu) * rs + be;
        if (br == 0) x1g[i] = val; else x2g[i] = val;
    }
    __syncthreads();

    // ---- relational tensor into LDS: ysl[p][r], p = u*25+v ----
    for (int p = tid; p < 625; p += 512) {
        int u = p / VV, v = p % VV;
        float Av = Amat[p];
        #pragma unroll
        for (int r = 0; r < RR; ++r) {
            float d = x1g[r * VV + u] - x1g[r * VV + v];
            float m = x2g[r * VV + u] * x2g[r * VV + v];
            ysl[p * 9 + r] = tanh_fast(d) + tanh_fast(m) + Av;   // ALPHA = 1
        }
    }
    __syncthreads();

    // ---- w4 GEMM + coalesced write: ys2[u][o][28] as float4 ----
    float* yn = ys2 + (size_t)n * YS2_SAMP;
    for (int e4 = tid; e4 < 11200; e4 += 512) {     // 25u * 64o * 7(float4)
        int u   = e4 / 448;                          // 448 = 64*7
        int rem = e4 - u * 448;
        int o   = rem / 7;
        int v4  = (rem - o * 7) * 4;
        float w[RR];
        #pragma unroll
        for (int r = 0; r < RR; ++r) w[r] = w4t[r * OO + o];
        const float bb = b4l[o];
        float4 out;
        float* op = &out.x;
        #pragma unroll
        for (int j = 0; j < 4; ++j) {
            int v = v4 + j;
            float a = 0.f;
            if (v < VV) {
                a = bb;
                const float* yr = &ysl[(u * VV + v) * 9];
                #pragma unroll
                for (int r = 0; r < RR; ++r) a += w[r] * yr[r];
            }
            op[j] = a;
        }
        *(float4*)(yn + u * (OO * 28) + o * 28 + v4) = out;
    }
}

// ---------------------------------------------------------------- kernel C1
// conv3 as a per-sample [64o x 64c] x [64c x 3200p] fp32 GEMM (unchanged).
__global__ __launch_bounds__(256) void kC1(const float* __restrict__ x,
    const float* __restrict__ w3, const float* __restrict__ b3,
    float* __restrict__ x3T)
{
    __shared__ float wt[CIN * 68];       // wt[c][o], stride 68 (17 KB)
    const int tid = threadIdx.x;
    const int n   = blockIdx.y;
    const int oq  = tid & 7;             // o in [8*oq, 8*oq+8)
    const int pg  = tid >> 3;            // 0..31
    const int p0  = blockIdx.x * 256 + pg * 8;

    for (int e = tid; e < CIN * OO; e += 256) {
        int o = e >> 6, c = e & 63;
        wt[c * 68 + o] = w3[e];
    }
    __syncthreads();

    float acc[8][8];                     // [o_local][p_local]
    #pragma unroll
    for (int i = 0; i < 8; ++i)
        #pragma unroll
        for (int j = 0; j < 8; ++j) acc[i][j] = 0.f;

    const bool act = (p0 < TVQ);
    const float* xp = x + (size_t)n * XSAMP + p0;
    if (act) {
        #pragma unroll 4
        for (int c = 0; c < CIN; ++c) {
            const float* xc = xp + c * TVQ;
            float4 xa = *(const float4*)(xc);
            float4 xb = *(const float4*)(xc + 4);
            const float* wr = &wt[c * 68 + oq * 8];
            float4 wa = *(const float4*)(wr);
            float4 wb = *(const float4*)(wr + 4);
            float xv[8] = {xa.x, xa.y, xa.z, xa.w, xb.x, xb.y, xb.z, xb.w};
            float wv[8] = {wa.x, wa.y, wa.z, wa.w, wb.x, wb.y, wb.z, wb.w};
            #pragma unroll
            for (int i = 0; i < 8; ++i)
                #pragma unroll
                for (int j = 0; j < 8; ++j)
                    acc[i][j] += wv[i] * xv[j];
        }
    }

    float bo[8];
    #pragma unroll
    for (int i = 0; i < 8; ++i) bo[i] = b3[oq * 8 + i];
    if (act) {
        float* dst = x3T + (size_t)n * X3_SAMP + (size_t)p0 * OO + oq * 8;
        #pragma unroll
        for (int j = 0; j < 8; ++j) {
            float4 s0, s1;
            s0.x = acc[0][j] + bo[0]; s0.y = acc[1][j] + bo[1];
            s0.z = acc[2][j] + bo[2]; s0.w = acc[3][j] + bo[3];
            s1.x = acc[4][j] + bo[4]; s1.y = acc[5][j] + bo[5];
            s1.z = acc[6][j] + bo[6]; s1.w = acc[7][j] + bo[7];
            *(float4*)(dst + j * OO)     = s0;
            *(float4*)(dst + j * OO + 4) = s1;
        }
    }
}

// ---------------------------------------------------------------- kernel C2
// Aggregation. ys2[u][o][28] is v-contiguous: float4 loads feed 8 FMAs.
// acc2 padded to 28 with zeros; ys2 pads are written 0 by kB.
__global__ __launch_bounds__(256) void kC2(const float* __restrict__ x3T,
    const float* __restrict__ ys2, float* __restrict__ y)
{
    __shared__ float lds[OO * 101];      // 25.9 KB (output transpose)
    const int tid = threadIdx.x;
    const int tc  = blockIdx.x;          // 0..15
    const int n   = blockIdx.y;
    const int t0  = tc * 8;
    const int o2  = tid & 63;
    const int th2 = tid >> 6;            // 0..3

    const float* xb = x3T + (size_t)n * X3_SAMP;
    float acc2[2][28];
    #pragma unroll
    for (int row = 0; row < 2; ++row) {
        const int t = t0 + 2 * th2 + row;
        #pragma unroll
        for (int v = 0; v < VV; ++v)
            acc2[row][v] = xb[(size_t)(t * VV + v) * OO + o2];
        acc2[row][25] = 0.f; acc2[row][26] = 0.f; acc2[row][27] = 0.f;
    }

    const float* yo = ys2 + (size_t)n * YS2_SAMP + o2 * 28;
    float res[2][VV];
    #pragma unroll
    for (int u = 0; u < VV; ++u) {
        const float* yu = yo + u * (OO * 28);
        float r0 = 0.f, r1 = 0.f;
        #pragma unroll
        for (int v4 = 0; v4 < 28; v4 += 4) {
            float4 w = *(const float4*)(yu + v4);
            r0 += w.x * acc2[0][v4]     + w.y * acc2[0][v4 + 1]
                + w.z * acc2[0][v4 + 2] + w.w * acc2[0][v4 + 3];
            r1 += w.x * acc2[1][v4]     + w.y * acc2[1][v4 + 1]
                + w.z * acc2[1][v4 + 2] + w.w * acc2[1][v4 + 3];
        }
        res[0][u] = r0;
        res[1][u] = r1;
    }

    float* yb = y + (size_t)n * YSAMP + t0 * VV;
    #pragma unroll 1
    for (int half = 0; half < 2; ++half) {
        __syncthreads();
        if ((th2 >> 1) == half) {
            #pragma unroll
            for (int row = 0; row < 2; ++row) {
                const int tl = (2 * th2 + row) & 3;
                #pragma unroll
                for (int u = 0; u < VV; ++u)
                    lds[o2 * 101 + tl * VV + u] = res[row][u];
            }
        }
        __syncthreads();
        for (int e = tid; e < 6400; e += 256) {
            int o = e / 100, m = e % 100;
            yb[o * TVQ + half * 100 + m] = lds[o * 101 + m];
        }
    }
}

// ---------------------------------------------------------------- kernel C (fallback)
// Fused conv3+aggregation, used only if the workspace cannot hold even one
// sample of x3T. ys2[u][o][28] layout.
__global__ __launch_bounds__(256) void kC(
    const float* __restrict__ x, const float* __restrict__ w3,
    const float* __restrict__ b3, const float* __restrict__ ys2,
    float* __restrict__ y)
{
    __shared__ float lds[7168];          // 28672 B
    const int tid = threadIdx.x;
    const int tc  = blockIdx.x;          // 0..15
    const int n   = blockIdx.y;
    const int t0  = tc * 8;

    const int og = tid >> 3;             // 0..31
    const int th = tid & 7;              // 0..7 (t-row)
    const int o0 = og * 2;

    float acc[2][VV];
    #pragma unroll
    for (int j = 0; j < 2; ++j)
        #pragma unroll
        for (int v = 0; v < VV; ++v) acc[j][v] = 0.f;

    const float* xn = x + (size_t)n * XSAMP + t0 * VV;
    #pragma unroll 1
    for (int cpass = 0; cpass < 2; ++cpass) {
        __syncthreads();
        for (int e4 = tid; e4 < 32 * 50; e4 += 256) {
            int cl = e4 / 50, r4 = (e4 % 50) * 4;
            float4 tv = *(const float4*)(xn + (cpass * 32 + cl) * TVQ + r4);
            float a[4] = {tv.x, tv.y, tv.z, tv.w};
            #pragma unroll
            for (int j = 0; j < 4; ++j) {
                int rem = r4 + j;
                lds[cl * 224 + (rem / VV) * 28 + (rem % VV)] = a[j];
            }
        }
        __syncthreads();
        #pragma unroll 1
        for (int q = 0; q < 2; ++q) {
            float w3q[2][16];
            #pragma unroll
            for (int j = 0; j < 2; ++j)
                #pragma unroll
                for (int k4 = 0; k4 < 4; ++k4) {
                    float4 wv = *(const float4*)(w3 + (o0 + j) * CIN
                                                 + cpass * 32 + q * 16 + k4 * 4);
                    w3q[j][k4*4+0] = wv.x; w3q[j][k4*4+1] = wv.y;
                    w3q[j][k4*4+2] = wv.z; w3q[j][k4*4+3] = wv.w;
                }
            #pragma unroll
            for (int ci = 0; ci < 16; ++ci) {
                const float* p = &lds[(q * 16 + ci) * 224 + th * 28];
                float4 a0 = *(const float4*)(p + 0);
                float4 a1 = *(const float4*)(p + 4);
                float4 a2 = *(const float4*)(p + 8);
                float4 a3 = *(const float4*)(p + 12);
                float4 a4 = *(const float4*)(p + 16);
                float4 a5 = *(const float4*)(p + 20);
                float  a6 = p[24];
                #pragma unroll
                for (int j = 0; j < 2; ++j) {
                    const float w = w3q[j][ci];
                    float* a = acc[j];
                    a[0]  += w*a0.x; a[1]  += w*a0.y; a[2]  += w*a0.z; a[3]  += w*a0.w;
                    a[4]  += w*a1.x; a[5]  += w*a1.y; a[6]  += w*a1.z; a[7]  += w*a1.w;
                    a[8]  += w*a2.x; a[9]  += w*a2.y; a[10] += w*a2.z; a[11] += w*a2.w;
                    a[12] += w*a3.x; a[13] += w*a3.y; a[14] += w*a3.z; a[15] += w*a3.w;
                    a[16] += w*a4.x; a[17] += w*a4.y; a[18] += w*a4.z; a[19] += w*a4.w;
                    a[20] += w*a5.x; a[21] += w*a5.y; a[22] += w*a5.z; a[23] += w*a5.w;
                    a[24] += w*a6;
                }
            }
        }
    }

    const int o2  = tid & 63;
    const int th2 = tid >> 6;            // 0..3, owns t = {2*th2, 2*th2+1}
    const float bias = b3[o2];
    float acc2[2][VV];

    #pragma unroll 1
    for (int half = 0; half < 2; ++half) {
        __syncthreads();
        if ((th >> 2) == half) {
            const int tl = th & 3;
            #pragma unroll
            for (int j = 0; j < 2; ++j)
                #pragma unroll
                for (int v = 0; v < VV; ++v)
                    lds[tl * 1601 + (o0 + j) * VV + v] = acc[j][v];
        }
        __syncthreads();
        if ((th2 >> 1) == half) {
            #pragma unroll
            for (int row = 0; row < 2; ++row) {
                const int tl = (2 * th2 + row) & 3;
                #pragma unroll
                for (int v = 0; v < VV; ++v)
                    acc2[row][v] = lds[tl * 1601 + o2 * VV + v];
            }
        }
    }
    #pragma unroll
    for (int row = 0; row < 2; ++row)
        #pragma unroll
        for (int v = 0; v < VV; ++v) acc2[row][v] += bias;

    const float* yT = ys2 + (size_t)n * YS2_SAMP + o2 * 28;
    float res[2][VV];
    #pragma unroll
    for (int u = 0; u < VV; ++u) {
        float r0 = 0.f, r1 = 0.f;
        #pragma unroll
        for (int v = 0; v < VV; ++v) {
            float yv = yT[u * (OO * 28) + v];
            r0 += yv * acc2[0][v];
            r1 += yv * acc2[1][v];
        }
        res[0][u] = r0;
        res[1][u] = r1;
    }

    float* yb = y + (size_t)n * YSAMP + t0 * VV;
    #pragma unroll 1
    for (int half = 0; half < 2; ++half) {
        __syncthreads();
        if ((th2 >> 1) == half) {
            #pragma unroll
            for (int row = 0; row < 2; ++row) {
                const int tl = (2 * th2 + row) & 3;
                #pragma unroll
                for (int u = 0; u < VV; ++u)
                    lds[o2 * 101 + tl * VV + u] = res[row][u];
            }
        }
        __syncthreads();
        for (int e = tid; e < 6400; e += 256) {
            int o = e / 100, m = e % 100;
            yb[o * TVQ + half * 100 + m] = lds[o * 101 + m];
        }
    }
}

// ---------------------------------------------------------------- launch
extern "C" void kernel_launch(void* const* d_in, const int* in_sizes, int n_in,
                              void* d_out, int out_size, void* d_ws, size_t ws_size,
                              hipStream_t stream)
{
    const float* x   = (const float*)d_in[0];
    const float* Am  = (const float*)d_in[1];
    const float* w1  = (const float*)d_in[2];
    const float* b1  = (const float*)d_in[3];
    const float* g1  = (const float*)d_in[4];
    const float* be1 = (const float*)d_in[5];
    const float* w2  = (const float*)d_in[6];
    const float* b2  = (const float*)d_in[7];
    const float* g2  = (const float*)d_in[8];
    const float* be2 = (const float*)d_in[9];
    const float* w3  = (const float*)d_in[10];
    const float* b3  = (const float*)d_in[11];
    const float* w4  = (const float*)d_in[12];
    const float* b4  = (const float*)d_in[13];
    float* y  = (float*)d_out;
    float* ws = (float*)d_ws;
    // workspace: s12g 128*400 | ssqg 128*2 | ys2 128*44800 | x3T up to
    // 128*204800 (~105 MB). Chunked / fused-fallback if ws smaller.
    float* s12g = ws;
    float* ssqg = s12g + (size_t)NN * S12N;
    float* ys2  = ssqg + (size_t)NN * 2;
    float* x3T  = ys2 + (size_t)NN * YS2_SAMP;

    const int nz = NN * S12N + NN * 2;
    hipLaunchKernelGGL(kZero, dim3((nz + 255) / 256), dim3(256), 0, stream, ws, nz);
    hipLaunchKernelGGL(kA, dim3(4, NN), dim3(256), 0, stream,
                       x, w1, b1, w2, b2, s12g, ssqg);
    hipLaunchKernelGGL(kB, dim3(NN), dim3(512), 0, stream,
                       s12g, ssqg, b1, g1, be1, b2, g2, be2, Am, w4, b4, ys2);

    const size_t baseF = (size_t)NN * S12N + NN * 2 + (size_t)NN * YS2_SAMP;
    const size_t wsF   = ws_size / sizeof(float);
    long availF = (long)wsF - (long)baseF;
    int chunk = 0;
    if (availF >= (long)X3_SAMP) {
        long c = availF / (long)X3_SAMP;
        chunk = (c > NN) ? NN : (int)c;
    }
    if (chunk >= 1) {
        for (int n0 = 0; n0 < NN; n0 += chunk) {
            int nc = (NN - n0 < chunk) ? (NN - n0) : chunk;
            hipLaunchKernelGGL(kC1, dim3(13, nc), dim3(256), 0, stream,
                               x + (size_t)n0 * XSAMP, w3, b3, x3T);
            hipLaunchKernelGGL(kC2, dim3(16, nc), dim3(256), 0, stream,
                               x3T, ys2 + (size_t)n0 * YS2_SAMP,
                               y + (size_t)n0 * YSAMP);
        }
    } else {
        hipLaunchKernelGGL(kC, dim3(16, NN), dim3(256), 0, stream,
                           x, w3, b3, ys2, y);
    }
}

// Round 5
// 444.188 us; speedup vs baseline: 1.3066x; 1.0218x over previous
//
#include <hip/hip_runtime.h>

// Problem constants (from reference): N=128, Cin=64, T=128, V=25, O=64, R=8
#define EPSV 1e-5f
constexpr int NN = 128, CIN = 64, TT = 128, VV = 25, OO = 64, RR = 8;
constexpr int TVQ   = TT * VV;        // 3200  (per-channel plane)
constexpr int XSAMP = CIN * TVQ;      // 204800 (per-sample x)
constexpr int YSAMP = OO * TT * VV;   // 819200 (per-sample y)
constexpr int RTV   = RR * TT * VV;   // 25600 (GroupNorm count)
constexpr int S12N  = 2 * RR * VV;    // 400   (s1+s2 per sample)
// ys3[n][u][v4][o][4]: relational tensor, v packed in 4s (25->28), o-major
// inner 4-pack so kC2 lane reads are 16B-stride coalesced.
constexpr int YS3_SAMP = VV * 7 * OO * 4;  // 44800
constexpr int X3_SAMP  = TVQ * OO;         // 204800: x3T[n][p][o], p = t*25+v

// ---------------------------------------------------------------- zero scratch
__global__ __launch_bounds__(256) void kZero(float* __restrict__ p, int n)
{
    int i = blockIdx.x * 256 + threadIdx.x;
    if (i < n) p[i] = 0.f;
}

// ---------------------------------------------------------------- kernel A
// (Proven R0/R2 version, verbatim.) One pass over x. Per block: (n, t-chunk
// of 32). 200 threads own 4 consecutive (t,v) points each (float4 loads,
// coalesced). Outputs: s12g[n][400] = sum_t conv_pre_bias, ssqg[n][2] =
// sum of squares (bias included).
__global__ __launch_bounds__(256) void kA(const float* __restrict__ x,
    const float* __restrict__ w1, const float* __restrict__ b1,
    const float* __restrict__ w2, const float* __restrict__ b2,
    float* __restrict__ s12g, float* __restrict__ ssqg)
{
    __shared__ float wt1[CIN * RR], wt2[CIN * RR];   // transposed [c][r]
    __shared__ float s1l[RR * VV], s2l[RR * VV];
    __shared__ float redA[4], redB[4];
    const int tid = threadIdx.x;
    const int tc  = blockIdx.x;   // 0..3  (32 t each)
    const int n   = blockIdx.y;

    for (int e = tid; e < CIN * RR; e += 256) {
        int r = e >> 6, c = e & 63;
        wt1[c * RR + r] = w1[e];
        wt2[c * RR + r] = w2[e];
    }
    for (int e = tid; e < 2 * RR * VV; e += 256) {
        if (e < RR * VV) s1l[e] = 0.f; else s2l[e - RR * VV] = 0.f;
    }
    __syncthreads();

    float acc1[4][RR], acc2[4][RR];
    #pragma unroll
    for (int j = 0; j < 4; ++j)
        #pragma unroll
        for (int r = 0; r < RR; ++r) { acc1[j][r] = 0.f; acc2[j][r] = 0.f; }

    const bool active = (tid < 200);
    const int p0 = tid * 4;                       // flat (t,v) offset in chunk
    const float* xb = x + (size_t)n * XSAMP + tc * 800 + p0;
    if (active) {
        #pragma unroll 4
        for (int c = 0; c < CIN; ++c) {
            float4 xv  = *(const float4*)(xb + c * TVQ);
            float4 wa1 = *(const float4*)(&wt1[c * RR]);
            float4 wb1 = *(const float4*)(&wt1[c * RR + 4]);
            float4 wa2 = *(const float4*)(&wt2[c * RR]);
            float4 wb2 = *(const float4*)(&wt2[c * RR + 4]);
            float xj[4]  = {xv.x, xv.y, xv.z, xv.w};
            float w1v[8] = {wa1.x, wa1.y, wa1.z, wa1.w, wb1.x, wb1.y, wb1.z, wb1.w};
            float w2v[8] = {wa2.x, wa2.y, wa2.z, wa2.w, wb2.x, wb2.y, wb2.z, wb2.w};
            #pragma unroll
            for (int j = 0; j < 4; ++j)
                #pragma unroll
                for (int r = 0; r < RR; ++r) {
                    acc1[j][r] += w1v[r] * xj[j];
                    acc2[j][r] += w2v[r] * xj[j];
                }
        }
    }

    float b1r[RR], b2r[RR];
    #pragma unroll
    for (int r = 0; r < RR; ++r) { b1r[r] = b1[r]; b2r[r] = b2[r]; }

    float ssq1 = 0.f, ssq2 = 0.f;
    if (active) {
        #pragma unroll
        for (int j = 0; j < 4; ++j) {
            int v = (p0 + j) % VV;
            #pragma unroll
            for (int r = 0; r < RR; ++r) {
                float c1 = acc1[j][r] + b1r[r]; ssq1 += c1 * c1;
                float c2 = acc2[j][r] + b2r[r]; ssq2 += c2 * c2;
                atomicAdd(&s1l[r * VV + v], acc1[j][r]);
                atomicAdd(&s2l[r * VV + v], acc2[j][r]);
            }
        }
    }
    #pragma unroll
    for (int off = 32; off > 0; off >>= 1) {
        ssq1 += __shfl_down(ssq1, off);
        ssq2 += __shfl_down(ssq2, off);
    }
    if ((tid & 63) == 0) { redA[tid >> 6] = ssq1; redB[tid >> 6] = ssq2; }
    __syncthreads();                               // LDS atomics + redA/B done
    for (int e = tid; e < S12N; e += 256) {
        float pv = (e < RR * VV) ? s1l[e] : s2l[e - RR * VV];
        atomicAdd(&s12g[n * S12N + e], pv);
    }
    if (tid == 0) {
        atomicAdd(&ssqg[n * 2 + 0], redA[0] + redA[1] + redA[2] + redA[3]);
        atomicAdd(&ssqg[n * 2 + 1], redB[0] + redB[1] + redB[2] + redB[3]);
    }
}

// ---------------------------------------------------------------- kernel B
__device__ __forceinline__ float tanh_fast(float v)
{
    float e = __expf(2.f * v);
    return 1.f - 2.f / (e + 1.f);    // safe at +/-inf of e
}

// Grid (5, NN), 512 threads: block owns 5 u's (640 blocks -> full chip).
// Stats preamble repeated per block (cheap). ysl[125][9] staged in LDS.
// Store loop ordered e4 = ul*448 + v4*64 + o: a wave = one (u,v4) x o=0..63,
// so ysl reads are wave-uniform BROADCASTS and the float4 stores to
// ys3[u][v4][o][4] are exactly-coalesced 1KB runs.
__global__ __launch_bounds__(512) void kB(
    const float* __restrict__ s12g, const float* __restrict__ ssqg,
    const float* __restrict__ b1, const float* __restrict__ g1, const float* __restrict__ be1,
    const float* __restrict__ b2, const float* __restrict__ g2, const float* __restrict__ be2,
    const float* __restrict__ Amat, const float* __restrict__ w4, const float* __restrict__ b4,
    float* __restrict__ ys3)
{
    __shared__ float x1g[RR * VV], x2g[RR * VV];
    __shared__ float w4t[RR * OO];       // transposed [r][o]
    __shared__ float b4l[OO];
    __shared__ float ysl[125 * 9];       // block's 5 u's: [ul*25+v][r]
    __shared__ float stats[2];
    __shared__ float mss[4];             // mu1, rs1, mu2, rs2
    const int tid = threadIdx.x;
    const int ub0 = blockIdx.x * 5;      // first u of this block
    const int n   = blockIdx.y;

    if (tid < 2) stats[tid] = 0.f;
    if (tid < OO * RR) {                 // w4[o][r] -> w4t[r][o]
        int o = tid >> 3, r = tid & 7;
        w4t[r * OO + o] = w4[tid];
    }
    if (tid < OO) b4l[tid] = b4[tid];
    __syncthreads();

    float sv = 0.f;
    if (tid < S12N) {
        sv = s12g[n * S12N + tid];
        atomicAdd(&stats[tid / (RR * VV)], sv);
    }
    __syncthreads();
    if (tid == 0) {
        float sb1 = 0.f, sb2 = 0.f;
        for (int r = 0; r < RR; ++r) { sb1 += b1[r]; sb2 += b2[r]; }
        float mu1 = (stats[0] + (float)(TT * VV) * sb1) / (float)RTV;
        float mu2 = (stats[1] + (float)(TT * VV) * sb2) / (float)RTV;
        float var1 = ssqg[n * 2 + 0] / (float)RTV - mu1 * mu1;
        float var2 = ssqg[n * 2 + 1] / (float)RTV - mu2 * mu2;
        mss[0] = mu1; mss[1] = rsqrtf(var1 + EPSV);
        mss[2] = mu2; mss[3] = rsqrtf(var2 + EPSV);
    }
    __syncthreads();
    if (tid < S12N) {
        int br = tid / (RR * VV);
        int i  = tid % (RR * VV);
        int r  = i / VV;
        float mu = mss[br * 2], rs = mss[br * 2 + 1];
        float mean_t = sv / (float)TT + (br ? b2[r] : b1[r]);
        float g  = br ? g2[r]  : g1[r];
        float be = br ? be2[r] : be1[r];
        float val = g * (mean_t - mu) * rs + be;
        if (br == 0) x1g[i] = val; else x2g[i] = val;
    }
    __syncthreads();

    // ---- relational tensor for this block's 5 u's: ysl[ul*25+v][r] ----
    for (int p = tid; p < 125; p += 512) {
        int u = ub0 + p / VV, v = p % VV;
        float Av = Amat[u * VV + v];
        #pragma unroll
        for (int r = 0; r < RR; ++r) {
            float d = x1g[r * VV + u] - x1g[r * VV + v];
            float m = x2g[r * VV + u] * x2g[r * VV + v];
            ysl[p * 9 + r] = tanh_fast(d) + tanh_fast(m) + Av;   // ALPHA = 1
        }
    }
    __syncthreads();

    // ---- w4 GEMM + coalesced write: ys3[u][v4][o][4] ----
    float* yn = ys3 + (size_t)n * YS3_SAMP + ub0 * (7 * OO * 4);
    for (int e4 = tid; e4 < 2240; e4 += 512) {      // 5ul * 7v4 * 64o
        int ul  = e4 / 448;                          // 448 = 7*64
        int rem = e4 - ul * 448;
        int v4  = rem >> 6;                          // 0..6
        int o   = rem & 63;
        float w[RR];
        #pragma unroll
        for (int r = 0; r < RR; ++r) w[r] = w4t[r * OO + o];
        const float bb = b4l[o];
        float4 out;
        float* op = &out.x;
        #pragma unroll
        for (int j = 0; j < 4; ++j) {
            int v = v4 * 4 + j;
            float a = 0.f;
            if (v < VV) {
                a = bb;
                const float* yr = &ysl[(ul * VV + v) * 9];   // wave-uniform
                #pragma unroll
                for (int r = 0; r < RR; ++r) a += w[r] * yr[r];
            }
            op[j] = a;
        }
        *(float4*)(yn + (size_t)e4 * 4) = out;       // lanes o -> contiguous 1KB
    }
}

// ---------------------------------------------------------------- kernel C1
// conv3 as a per-sample [64o x 64c] x [64c x 3200p] fp32 GEMM (unchanged).
__global__ __launch_bounds__(256) void kC1(const float* __restrict__ x,
    const float* __restrict__ w3, const float* __restrict__ b3,
    float* __restrict__ x3T)
{
    __shared__ float wt[CIN * 68];       // wt[c][o], stride 68 (17 KB)
    const int tid = threadIdx.x;
    const int n   = blockIdx.y;
    const int oq  = tid & 7;             // o in [8*oq, 8*oq+8)
    const int pg  = tid >> 3;            // 0..31
    const int p0  = blockIdx.x * 256 + pg * 8;

    for (int e = tid; e < CIN * OO; e += 256) {
        int o = e >> 6, c = e & 63;
        wt[c * 68 + o] = w3[e];
    }
    __syncthreads();

    float acc[8][8];                     // [o_local][p_local]
    #pragma unroll
    for (int i = 0; i < 8; ++i)
        #pragma unroll
        for (int j = 0; j < 8; ++j) acc[i][j] = 0.f;

    const bool act = (p0 < TVQ);
    const float* xp = x + (size_t)n * XSAMP + p0;
    if (act) {
        #pragma unroll 4
        for (int c = 0; c < CIN; ++c) {
            const float* xc = xp + c * TVQ;
            float4 xa = *(const float4*)(xc);
            float4 xb = *(const float4*)(xc + 4);
            const float* wr = &wt[c * 68 + oq * 8];
            float4 wa = *(const float4*)(wr);
            float4 wb = *(const float4*)(wr + 4);
            float xv[8] = {xa.x, xa.y, xa.z, xa.w, xb.x, xb.y, xb.z, xb.w};
            float wv[8] = {wa.x, wa.y, wa.z, wa.w, wb.x, wb.y, wb.z, wb.w};
            #pragma unroll
            for (int i = 0; i < 8; ++i)
                #pragma unroll
                for (int j = 0; j < 8; ++j)
                    acc[i][j] += wv[i] * xv[j];
        }
    }

    float bo[8];
    #pragma unroll
    for (int i = 0; i < 8; ++i) bo[i] = b3[oq * 8 + i];
    if (act) {
        float* dst = x3T + (size_t)n * X3_SAMP + (size_t)p0 * OO + oq * 8;
        #pragma unroll
        for (int j = 0; j < 8; ++j) {
            float4 s0, s1;
            s0.x = acc[0][j] + bo[0]; s0.y = acc[1][j] + bo[1];
            s0.z = acc[2][j] + bo[2]; s0.w = acc[3][j] + bo[3];
            s1.x = acc[4][j] + bo[4]; s1.y = acc[5][j] + bo[5];
            s1.z = acc[6][j] + bo[6]; s1.w = acc[7][j] + bo[7];
            *(float4*)(dst + j * OO)     = s0;
            *(float4*)(dst + j * OO + 4) = s1;
        }
    }
}

// ---------------------------------------------------------------- kernel C2
// Aggregation. ys3[u][v4][o][4]: lane o2 reads float4 at 16B lane stride ->
// every wave load is one contiguous 1KB transaction (was 112B stride, ~56
// cache lines per instr). x3T loads coalesced 256B. Output via proven 2-half
// LDS transpose.
__global__ __launch_bounds__(256) void kC2(const float* __restrict__ x3T,
    const float* __restrict__ ys3, float* __restrict__ y)
{
    __shared__ float lds[OO * 101];      // 25.9 KB (output transpose)
    const int tid = threadIdx.x;
    const int tc  = blockIdx.x;          // 0..15
    const int n   = blockIdx.y;
    const int t0  = tc * 8;
    const int o2  = tid & 63;
    const int th2 = tid >> 6;            // 0..3

    const float* xb = x3T + (size_t)n * X3_SAMP;
    float acc2[2][28];
    #pragma unroll
    for (int row = 0; row < 2; ++row) {
        const int t = t0 + 2 * th2 + row;
        #pragma unroll
        for (int v = 0; v < VV; ++v)
            acc2[row][v] = xb[(size_t)(t * VV + v) * OO + o2];
        acc2[row][25] = 0.f; acc2[row][26] = 0.f; acc2[row][27] = 0.f;
    }

    const float* yo = ys3 + (size_t)n * YS3_SAMP + o2 * 4;
    float res[2][VV];
    #pragma unroll
    for (int u = 0; u < VV; ++u) {
        const float* yu = yo + u * (7 * OO * 4);
        float r0 = 0.f, r1 = 0.f;
        #pragma unroll
        for (int v4 = 0; v4 < 7; ++v4) {
            float4 w = *(const float4*)(yu + v4 * (OO * 4));
            r0 += w.x * acc2[0][v4*4]     + w.y * acc2[0][v4*4 + 1]
                + w.z * acc2[0][v4*4 + 2] + w.w * acc2[0][v4*4 + 3];
            r1 += w.x * acc2[1][v4*4]     + w.y * acc2[1][v4*4 + 1]
                + w.z * acc2[1][v4*4 + 2] + w.w * acc2[1][v4*4 + 3];
        }
        res[0][u] = r0;
        res[1][u] = r1;
    }

    float* yb = y + (size_t)n * YSAMP + t0 * VV;
    #pragma unroll 1
    for (int half = 0; half < 2; ++half) {
        __syncthreads();
        if ((th2 >> 1) == half) {
            #pragma unroll
            for (int row = 0; row < 2; ++row) {
                const int tl = (2 * th2 + row) & 3;
                #pragma unroll
                for (int u = 0; u < VV; ++u)
                    lds[o2 * 101 + tl * VV + u] = res[row][u];
            }
        }
        __syncthreads();
        for (int e = tid; e < 6400; e += 256) {
            int o = e / 100, m = e % 100;
            yb[o * TVQ + half * 100 + m] = lds[o * 101 + m];
        }
    }
}

// ---------------------------------------------------------------- kernel C (fallback)
// Fused conv3+aggregation, used only if the workspace cannot hold even one
// sample of x3T. ys3[u][v4][o][4] layout.
__global__ __launch_bounds__(256) void kC(
    const float* __restrict__ x, const float* __restrict__ w3,
    const float* __restrict__ b3, const float* __restrict__ ys3,
    float* __restrict__ y)
{
    __shared__ float lds[7168];          // 28672 B
    const int tid = threadIdx.x;
    const int tc  = blockIdx.x;          // 0..15
    const int n   = blockIdx.y;
    const int t0  = tc * 8;

    const int og = tid >> 3;             // 0..31
    const int th = tid & 7;              // 0..7 (t-row)
    const int o0 = og * 2;

    float acc[2][VV];
    #pragma unroll
    for (int j = 0; j < 2; ++j)
        #pragma unroll
        for (int v = 0; v < VV; ++v) acc[j][v] = 0.f;

    const float* xn = x + (size_t)n * XSAMP + t0 * VV;
    #pragma unroll 1
    for (int cpass = 0; cpass < 2; ++cpass) {
        __syncthreads();
        for (int e4 = tid; e4 < 32 * 50; e4 += 256) {
            int cl = e4 / 50, r4 = (e4 % 50) * 4;
            float4 tv = *(const float4*)(xn + (cpass * 32 + cl) * TVQ + r4);
            float a[4] = {tv.x, tv.y, tv.z, tv.w};
            #pragma unroll
            for (int j = 0; j < 4; ++j) {
                int rem = r4 + j;
                lds[cl * 224 + (rem / VV) * 28 + (rem % VV)] = a[j];
            }
        }
        __syncthreads();
        #pragma unroll 1
        for (int q = 0; q < 2; ++q) {
            float w3q[2][16];
            #pragma unroll
            for (int j = 0; j < 2; ++j)
                #pragma unroll
                for (int k4 = 0; k4 < 4; ++k4) {
                    float4 wv = *(const float4*)(w3 + (o0 + j) * CIN
                                                 + cpass * 32 + q * 16 + k4 * 4);
                    w3q[j][k4*4+0] = wv.x; w3q[j][k4*4+1] = wv.y;
                    w3q[j][k4*4+2] = wv.z; w3q[j][k4*4+3] = wv.w;
                }
            #pragma unroll
            for (int ci = 0; ci < 16; ++ci) {
                const float* p = &lds[(q * 16 + ci) * 224 + th * 28];
                float4 a0 = *(const float4*)(p + 0);
                float4 a1 = *(const float4*)(p + 4);
                float4 a2 = *(const float4*)(p + 8);
                float4 a3 = *(const float4*)(p + 12);
                float4 a4 = *(const float4*)(p + 16);
                float4 a5 = *(const float4*)(p + 20);
                float  a6 = p[24];
                #pragma unroll
                for (int j = 0; j < 2; ++j) {
                    const float w = w3q[j][ci];
                    float* a = acc[j];
                    a[0]  += w*a0.x; a[1]  += w*a0.y; a[2]  += w*a0.z; a[3]  += w*a0.w;
                    a[4]  += w*a1.x; a[5]  += w*a1.y; a[6]  += w*a1.z; a[7]  += w*a1.w;
                    a[8]  += w*a2.x; a[9]  += w*a2.y; a[10] += w*a2.z; a[11] += w*a2.w;
                    a[12] += w*a3.x; a[13] += w*a3.y; a[14] += w*a3.z; a[15] += w*a3.w;
                    a[16] += w*a4.x; a[17] += w*a4.y; a[18] += w*a4.z; a[19] += w*a4.w;
                    a[20] += w*a5.x; a[21] += w*a5.y; a[22] += w*a5.z; a[23] += w*a5.w;
                    a[24] += w*a6;
                }
            }
        }
    }

    const int o2  = tid & 63;
    const int th2 = tid >> 6;            // 0..3, owns t = {2*th2, 2*th2+1}
    const float bias = b3[o2];
    float acc2[2][VV];

    #pragma unroll 1
    for (int half = 0; half < 2; ++half) {
        __syncthreads();
        if ((th >> 2) == half) {
            const int tl = th & 3;
            #pragma unroll
            for (int j = 0; j < 2; ++j)
                #pragma unroll
                for (int v = 0; v < VV; ++v)
                    lds[tl * 1601 + (o0 + j) * VV + v] = acc[j][v];
        }
        __syncthreads();
        if ((th2 >> 1) == half) {
            #pragma unroll
            for (int row = 0; row < 2; ++row) {
                const int tl = (2 * th2 + row) & 3;
                #pragma unroll
                for (int v = 0; v < VV; ++v)
                    acc2[row][v] = lds[tl * 1601 + o2 * VV + v];
            }
        }
    }
    #pragma unroll
    for (int row = 0; row < 2; ++row)
        #pragma unroll
        for (int v = 0; v < VV; ++v) acc2[row][v] += bias;

    const float* yT = ys3 + (size_t)n * YS3_SAMP + o2 * 4;
    float res[2][VV];
    #pragma unroll
    for (int u = 0; u < VV; ++u) {
        float r0 = 0.f, r1 = 0.f;
        #pragma unroll
        for (int v = 0; v < VV; ++v) {
            float yv = yT[u * (7 * OO * 4) + (v >> 2) * (OO * 4) + (v & 3)];
            r0 += yv * acc2[0][v];
            r1 += yv * acc2[1][v];
        }
        res[0][u] = r0;
        res[1][u] = r1;
    }

    float* yb = y + (size_t)n * YSAMP + t0 * VV;
    #pragma unroll 1
    for (int half = 0; half < 2; ++half) {
        __syncthreads();
        if ((th2 >> 1) == half) {
            #pragma unroll
            for (int row = 0; row < 2; ++row) {
                const int tl = (2 * th2 + row) & 3;
                #pragma unroll
                for (int u = 0; u < VV; ++u)
                    lds[o2 * 101 + tl * VV + u] = res[row][u];
            }
        }
        __syncthreads();
        for (int e = tid; e < 6400; e += 256) {
            int o = e / 100, m = e % 100;
            yb[o * TVQ + half * 100 + m] = lds[o * 101 + m];
        }
    }
}

// ---------------------------------------------------------------- launch
extern "C" void kernel_launch(void* const* d_in, const int* in_sizes, int n_in,
                              void* d_out, int out_size, void* d_ws, size_t ws_size,
                              hipStream_t stream)
{
    const float* x   = (const float*)d_in[0];
    const float* Am  = (const float*)d_in[1];
    const float* w1  = (const float*)d_in[2];
    const float* b1  = (const float*)d_in[3];
    const float* g1  = (const float*)d_in[4];
    const float* be1 = (const float*)d_in[5];
    const float* w2  = (const float*)d_in[6];
    const float* b2  = (const float*)d_in[7];
    const float* g2  = (const float*)d_in[8];
    const float* be2 = (const float*)d_in[9];
    const float* w3  = (const float*)d_in[10];
    const float* b3  = (const float*)d_in[11];
    const float* w4  = (const float*)d_in[12];
    const float* b4  = (const float*)d_in[13];
    float* y  = (float*)d_out;
    float* ws = (float*)d_ws;
    // workspace: s12g 128*400 | ssqg 128*2 | ys3 128*44800 | x3T up to
    // 128*204800 (~105 MB). Chunked / fused-fallback if ws smaller.
    float* s12g = ws;
    float* ssqg = s12g + (size_t)NN * S12N;
    float* ys3  = ssqg + (size_t)NN * 2;
    float* x3T  = ys3 + (size_t)NN * YS3_SAMP;

    const int nz = NN * S12N + NN * 2;
    hipLaunchKernelGGL(kZero, dim3((nz + 255) / 256), dim3(256), 0, stream, ws, nz);
    hipLaunchKernelGGL(kA, dim3(4, NN), dim3(256), 0, stream,
                       x, w1, b1, w2, b2, s12g, ssqg);
    hipLaunchKernelGGL(kB, dim3(5, NN), dim3(512), 0, stream,
                       s12g, ssqg, b1, g1, be1, b2, g2, be2, Am, w4, b4, ys3);

    const size_t baseF = (size_t)NN * S12N + NN * 2 + (size_t)NN * YS3_SAMP;
    const size_t wsF   = ws_size / sizeof(float);
    long availF = (long)wsF - (long)baseF;
    int chunk = 0;
    if (availF >= (long)X3_SAMP) {
        long c = availF / (long)X3_SAMP;
        chunk = (c > NN) ? NN : (int)c;
    }
    if (chunk >= 1) {
        for (int n0 = 0; n0 < NN; n0 += chunk) {
            int nc = (NN - n0 < chunk) ? (NN - n0) : chunk;
            hipLaunchKernelGGL(kC1, dim3(13, nc), dim3(256), 0, stream,
                               x + (size_t)n0 * XSAMP, w3, b3, x3T);
            hipLaunchKernelGGL(kC2, dim3(16, nc), dim3(256), 0, stream,
                               x3T, ys3 + (size_t)n0 * YS3_SAMP,
                               y + (size_t)n0 * YSAMP);
        }
    } else {
        hipLaunchKernelGGL(kC, dim3(16, NN), dim3(256), 0, stream,
                           x, w3, b3, ys3, y);
    }
}